// Round 1
// baseline (552.035 us; speedup 1.0000x reference)
//
#include <hip/hip_runtime.h>

typedef __attribute__((ext_vector_type(8))) short short8;
typedef __attribute__((ext_vector_type(4))) float f32x4;
typedef unsigned short u16;

#define SCALE_ 0.125f

__device__ __forceinline__ u16 f2bf(float x) {
  union { float f; unsigned u; } c; c.f = x;
  unsigned u = c.u;
  unsigned r = (u + 0x7fffu + ((u >> 16) & 1u)) >> 16;  // RNE
  return (u16)r;
}

__device__ __forceinline__ short8 cvt8(float4 x0, float4 x1) {
  short8 v;
  v[0]=(short)f2bf(x0.x); v[1]=(short)f2bf(x0.y); v[2]=(short)f2bf(x0.z); v[3]=(short)f2bf(x0.w);
  v[4]=(short)f2bf(x1.x); v[5]=(short)f2bf(x1.y); v[6]=(short)f2bf(x1.z); v[7]=(short)f2bf(x1.w);
  return v;
}

// C(128x128) = A(128x1024) * B(128x1024)^T for this block.
// A: fp32 (AMODE 0) or bf16 (AMODE 1); B (weights): fp32, converted on the fly.
// LDS tiles [128 rows][64 cols bf16] with XOR swizzle on 16B slots: slot ^ (row&7).
template<int AMODE>
__device__ __forceinline__ void gemm_core(const void* __restrict__ Ap,
                                          const float* __restrict__ W,
                                          u16* As, u16* Bs,
                                          int bm0, int bn0, f32x4 acc[4][4])
{
  const int tid = threadIdx.x;
  const int lane = tid & 63, wid = tid >> 6;
  const int lo = lane & 15, hi = lane >> 4;
  const int wr0 = (wid >> 1) * 64, wc0 = (wid & 1) * 64;
  const float* Af = (const float*)Ap;
  const u16*   Ab = (const u16*)Ap;

  for (int k0 = 0; k0 < 1024; k0 += 64) {
    __syncthreads();
#pragma unroll
    for (int it = 0; it < 4; ++it) {
      int idx = it * 256 + tid;          // 1024 ids: 128 rows x 8 slots
      int row = idx >> 3, slot = idx & 7;
      int gc = k0 + slot * 8;
      short8 v;
      if (AMODE == 0) {
        const float* s = Af + (size_t)(bm0 + row) * 1024 + gc;
        v = cvt8(*(const float4*)s, *(const float4*)(s + 4));
      } else {
        v = *(const short8*)(Ab + (size_t)(bm0 + row) * 1024 + gc);
      }
      *(short8*)(&As[row * 64 + ((slot ^ (row & 7)) << 3)]) = v;
      const float* sw = W + (size_t)(bn0 + row) * 1024 + gc;
      short8 w = cvt8(*(const float4*)sw, *(const float4*)(sw + 4));
      *(short8*)(&Bs[row * 64 + ((slot ^ (row & 7)) << 3)]) = w;
    }
    __syncthreads();
#pragma unroll
    for (int kk = 0; kk < 2; ++kk) {
      short8 af[4], bfr[4];
      int slot = kk * 4 + hi;
#pragma unroll
      for (int i = 0; i < 4; ++i) {
        int row = wr0 + i * 16 + lo;
        af[i] = *(const short8*)(&As[row * 64 + ((slot ^ (row & 7)) << 3)]);
      }
#pragma unroll
      for (int j = 0; j < 4; ++j) {
        int row = wc0 + j * 16 + lo;
        bfr[j] = *(const short8*)(&Bs[row * 64 + ((slot ^ (row & 7)) << 3)]);
      }
#pragma unroll
      for (int i = 0; i < 4; ++i)
#pragma unroll
        for (int j = 0; j < 4; ++j)
          acc[i][j] = __builtin_amdgcn_mfma_f32_16x16x32_bf16(af[i], bfr[j], acc[i][j], 0, 0, 0);
    }
  }
}

// z=0: Q -> Qh[bh][s][d]; z=1: K -> Kh[bh][s][d]; z=2: V -> Vt[bh][d][s]
__global__ __launch_bounds__(256) void gemm_qkv(
    const float* __restrict__ xq, const float* __restrict__ xk, const float* __restrict__ xv,
    const float* __restrict__ Wq, const float* __restrict__ Wk, const float* __restrict__ Wv,
    const float* __restrict__ bq, const float* __restrict__ bk, const float* __restrict__ bv,
    u16* __restrict__ Qh, u16* __restrict__ Kh, u16* __restrict__ Vt)
{
  __shared__ __align__(16) u16 As[128 * 64];
  __shared__ __align__(16) u16 Bs[128 * 64];
  const int z = blockIdx.z;
  const float* A    = (z == 0) ? xq : (z == 1) ? xk : xv;
  const float* W    = (z == 0) ? Wq : (z == 1) ? Wk : Wv;
  const float* bias = (z == 0) ? bq : (z == 1) ? bk : bv;
  u16* out          = (z == 0) ? Qh : (z == 1) ? Kh : Vt;
  const int bm0 = blockIdx.x * 128, bn0 = blockIdx.y * 128;
  f32x4 acc[4][4] = {};
  gemm_core<0>(A, W, As, Bs, bm0, bn0, acc);

  const int lane = threadIdx.x & 63, wid = threadIdx.x >> 6;
  const int lo = lane & 15, hi = lane >> 4;
  const int wr0 = (wid >> 1) * 64, wc0 = (wid & 1) * 64;
#pragma unroll
  for (int j = 0; j < 4; ++j) {
    int n = bn0 + wc0 + j * 16 + lo;
    float bb = bias[n];
    int h = n >> 6, d = n & 63;
#pragma unroll
    for (int i = 0; i < 4; ++i) {
#pragma unroll
      for (int r = 0; r < 4; ++r) {
        int m = bm0 + wr0 + i * 16 + hi * 4 + r;
        int b = m >> 11, s = m & 2047;
        float v = acc[i][j][r] + bb;
        size_t bh = (size_t)(b * 16 + h);
        if (z < 2) out[(bh * 2048 + (size_t)s) * 64 + d] = f2bf(v);
        else       out[(bh * 64 + (size_t)d) * 2048 + s] = f2bf(v);
      }
    }
  }
}

__global__ __launch_bounds__(256) void gemm_out(
    const u16* __restrict__ ATT, const float* __restrict__ Wo,
    const float* __restrict__ bo, float* __restrict__ out)
{
  __shared__ __align__(16) u16 As[128 * 64];
  __shared__ __align__(16) u16 Bs[128 * 64];
  const int bm0 = blockIdx.x * 128, bn0 = blockIdx.y * 128;
  f32x4 acc[4][4] = {};
  gemm_core<1>(ATT, Wo, As, Bs, bm0, bn0, acc);

  const int lane = threadIdx.x & 63, wid = threadIdx.x >> 6;
  const int lo = lane & 15, hi = lane >> 4;
  const int wr0 = (wid >> 1) * 64, wc0 = (wid & 1) * 64;
#pragma unroll
  for (int j = 0; j < 4; ++j) {
    int n = bn0 + wc0 + j * 16 + lo;
    float bb = bo[n];
#pragma unroll
    for (int i = 0; i < 4; ++i)
#pragma unroll
      for (int r = 0; r < 4; ++r) {
        int m = bm0 + wr0 + i * 16 + hi * 4 + r;
        out[(size_t)m * 1024 + n] = acc[i][j][r] + bb;
      }
  }
}

// One block = 64 q-rows of one (b,h). 4 waves x 16 q-rows. KVBLK = 64.
// Pass 1: online max/sum over all 32 K-tiles. Pass 2: recompute S, normalize,
// write attn (fp32, nontemporal), P->LDS bf16, PV MFMA accumulate.
__global__ __launch_bounds__(256) void attn_fused(
    const u16* __restrict__ Qh, const u16* __restrict__ Kh,
    const u16* __restrict__ Vt, float* __restrict__ attnOut,
    u16* __restrict__ ATT)
{
  __shared__ __align__(16) u16 Qs[64 * 64];
  __shared__ __align__(16) u16 Ks[64 * 64];
  __shared__ __align__(16) u16 Vs[64 * 64];
  __shared__ __align__(16) u16 Ps[64 * 64];
  const int tid = threadIdx.x, lane = tid & 63, wid = tid >> 6;
  const int lo = lane & 15, hi = lane >> 4;
  const int q0 = blockIdx.x * 64;
  const int bh = blockIdx.y;
  const int wq0 = wid * 16;

  const u16* Qg  = Qh + ((size_t)bh * 2048 + q0) * 64;
  const u16* Kg0 = Kh + (size_t)bh * 2048 * 64;
  const u16* Vg0 = Vt + (size_t)bh * 64 * 2048;

#pragma unroll
  for (int it = 0; it < 2; ++it) {
    int idx = it * 256 + tid;
    int row = idx >> 3, slot = idx & 7;
    short8 v = *(const short8*)(Qg + row * 64 + slot * 8);
    *(short8*)(&Qs[row * 64 + ((slot ^ (row & 7)) << 3)]) = v;
  }
  __syncthreads();
  short8 qa[2];
#pragma unroll
  for (int kk = 0; kk < 2; ++kk) {
    int row = wq0 + lo, slot = kk * 4 + hi;
    qa[kk] = *(const short8*)(&Qs[row * 64 + ((slot ^ (row & 7)) << 3)]);
  }

  float m_r[4], l_r[4];
#pragma unroll
  for (int r = 0; r < 4; ++r) { m_r[r] = -1e30f; l_r[r] = 0.f; }

  // ---- pass 1: softmax stats ----
  for (int kt = 0; kt < 32; ++kt) {
    __syncthreads();
    int t0 = kt * 64;
#pragma unroll
    for (int it = 0; it < 2; ++it) {
      int idx = it * 256 + tid;
      int row = idx >> 3, slot = idx & 7;
      short8 v = *(const short8*)(Kg0 + (size_t)(t0 + row) * 64 + slot * 8);
      *(short8*)(&Ks[row * 64 + ((slot ^ (row & 7)) << 3)]) = v;
    }
    __syncthreads();
    f32x4 sc[4] = {};
#pragma unroll
    for (int kk = 0; kk < 2; ++kk) {
      int slot = kk * 4 + hi;
#pragma unroll
      for (int j = 0; j < 4; ++j) {
        int row = j * 16 + lo;
        short8 kb = *(const short8*)(&Ks[row * 64 + ((slot ^ (row & 7)) << 3)]);
        sc[j] = __builtin_amdgcn_mfma_f32_16x16x32_bf16(qa[kk], kb, sc[j], 0, 0, 0);
      }
    }
    float tmax[4];
#pragma unroll
    for (int r = 0; r < 4; ++r) {
      sc[0][r] *= SCALE_; sc[1][r] *= SCALE_; sc[2][r] *= SCALE_; sc[3][r] *= SCALE_;
      tmax[r] = fmaxf(fmaxf(sc[0][r], sc[1][r]), fmaxf(sc[2][r], sc[3][r]));
    }
#pragma unroll
    for (int off = 1; off < 16; off <<= 1)
#pragma unroll
      for (int r = 0; r < 4; ++r)
        tmax[r] = fmaxf(tmax[r], __shfl_xor(tmax[r], off));
#pragma unroll
    for (int r = 0; r < 4; ++r) {
      float nm = fmaxf(m_r[r], tmax[r]);
      float ts = __expf(sc[0][r] - nm) + __expf(sc[1][r] - nm)
               + __expf(sc[2][r] - nm) + __expf(sc[3][r] - nm);
#pragma unroll
      for (int off = 1; off < 16; off <<= 1) ts += __shfl_xor(ts, off);
      l_r[r] = l_r[r] * __expf(m_r[r] - nm) + ts;
      m_r[r] = nm;
    }
  }
  float inv_l[4];
#pragma unroll
  for (int r = 0; r < 4; ++r) inv_l[r] = 1.0f / l_r[r];

  // ---- pass 2: write attn + PV ----
  f32x4 oacc[4] = {};
  for (int kt = 0; kt < 32; ++kt) {
    __syncthreads();
    int t0 = kt * 64;
#pragma unroll
    for (int it = 0; it < 2; ++it) {
      int idx = it * 256 + tid;
      int row = idx >> 3, slot = idx & 7;
      short8 v = *(const short8*)(Kg0 + (size_t)(t0 + row) * 64 + slot * 8);
      *(short8*)(&Ks[row * 64 + ((slot ^ (row & 7)) << 3)]) = v;
      short8 w = *(const short8*)(Vg0 + (size_t)row * 2048 + t0 + slot * 8);
      *(short8*)(&Vs[row * 64 + ((slot ^ (row & 7)) << 3)]) = w;
    }
    __syncthreads();
    f32x4 sc[4] = {};
#pragma unroll
    for (int kk = 0; kk < 2; ++kk) {
      int slot = kk * 4 + hi;
#pragma unroll
      for (int j = 0; j < 4; ++j) {
        int row = j * 16 + lo;
        short8 kb = *(const short8*)(&Ks[row * 64 + ((slot ^ (row & 7)) << 3)]);
        sc[j] = __builtin_amdgcn_mfma_f32_16x16x32_bf16(qa[kk], kb, sc[j], 0, 0, 0);
      }
    }
    float* aOut = attnOut + ((size_t)bh * 2048 + (size_t)(q0 + wq0 + hi * 4)) * 2048 + t0;
#pragma unroll
    for (int j = 0; j < 4; ++j) {
#pragma unroll
      for (int r = 0; r < 4; ++r) {
        float p = __expf(sc[j][r] * SCALE_ - m_r[r]) * inv_l[r];
        __builtin_nontemporal_store(p, aOut + (size_t)r * 2048 + j * 16 + lo);
        int ql = wq0 + hi * 4 + r, tl = j * 16 + lo;
        Ps[ql * 64 + (((tl >> 3) ^ (ql & 7)) << 3) + (tl & 7)] = f2bf(p);
      }
    }
    __syncthreads();
#pragma unroll
    for (int kk = 0; kk < 2; ++kk) {
      int slot = kk * 4 + hi;
      int prow = wq0 + lo;
      short8 pa = *(const short8*)(&Ps[prow * 64 + ((slot ^ (prow & 7)) << 3)]);
#pragma unroll
      for (int j = 0; j < 4; ++j) {
        int vrow = j * 16 + lo;
        short8 vb = *(const short8*)(&Vs[vrow * 64 + ((slot ^ (vrow & 7)) << 3)]);
        oacc[j] = __builtin_amdgcn_mfma_f32_16x16x32_bf16(pa, vb, oacc[j], 0, 0, 0);
      }
    }
  }
  // attended -> ATT[b*2048+q][h*64+d] bf16
  const int b = bh >> 4, h = bh & 15;
#pragma unroll
  for (int j = 0; j < 4; ++j)
#pragma unroll
    for (int r = 0; r < 4; ++r) {
      int ql = wq0 + hi * 4 + r;
      int d = j * 16 + lo;
      size_t row = (size_t)b * 2048 + q0 + ql;
      ATT[row * 1024 + h * 64 + d] = f2bf(oacc[j][r]);
    }
}

extern "C" void kernel_launch(void* const* d_in, const int* in_sizes, int n_in,
                              void* d_out, int out_size, void* d_ws, size_t ws_size,
                              hipStream_t stream) {
  const float* query = (const float*)d_in[0];
  const float* key   = (const float*)d_in[1];
  const float* value = (const float*)d_in[2];
  const float* Wq = (const float*)d_in[3];
  const float* bq = (const float*)d_in[4];
  const float* Wk = (const float*)d_in[5];
  const float* bk = (const float*)d_in[6];
  const float* Wv = (const float*)d_in[7];
  const float* bv = (const float*)d_in[8];
  const float* Wo = (const float*)d_in[9];
  const float* bo = (const float*)d_in[10];

  u16* Qh  = (u16*)d_ws;           // 8388608 bf16
  u16* Kh  = Qh + 8388608;
  u16* Vt  = Kh + 8388608;
  u16* ATT = Vt + 8388608;

  float* outO  = (float*)d_out;
  float* attnO = outO + (size_t)8388608;

  dim3 blk(256);
  gemm_qkv<<<dim3(64, 8, 3), blk, 0, stream>>>(query, key, value, Wq, Wk, Wv,
                                               bq, bk, bv, Qh, Kh, Vt);
  attn_fused<<<dim3(32, 64), blk, 0, stream>>>(Qh, Kh, Vt, attnO, ATT);
  gemm_out<<<dim3(64, 8), blk, 0, stream>>>(ATT, Wo, bo, outO);
}

// Round 3
// 474.958 us; speedup vs baseline: 1.1623x; 1.1623x over previous
//
#include <hip/hip_runtime.h>

typedef __attribute__((ext_vector_type(8))) short short8;
typedef __attribute__((ext_vector_type(4))) float f32x4;
typedef unsigned short u16;
typedef unsigned int u32;

#define AS1 __attribute__((address_space(1)))
#define AS3 __attribute__((address_space(3)))

__device__ __forceinline__ void cp16(const void* g, void* l) {
  __builtin_amdgcn_global_load_lds((const AS1 u32*)g, (AS3 u32*)l, 16, 0, 0);
}

__device__ __forceinline__ u16 f2bf(float x) {
  union { float f; unsigned u; } c; c.f = x;
  unsigned u = c.u;
  unsigned r = (u + 0x7fffu + ((u >> 16) & 1u)) >> 16;  // RNE
  return (u16)r;
}

__device__ __forceinline__ short8 cvt8(float4 x0, float4 x1) {
  short8 v;
  v[0]=(short)f2bf(x0.x); v[1]=(short)f2bf(x0.y); v[2]=(short)f2bf(x0.z); v[3]=(short)f2bf(x0.w);
  v[4]=(short)f2bf(x1.x); v[5]=(short)f2bf(x1.y); v[6]=(short)f2bf(x1.z); v[7]=(short)f2bf(x1.w);
  return v;
}

// -------- convert fp32 -> bf16: query,key,value -> Xb; Wq,Wk,Wv,Wo -> Wb ----
__global__ __launch_bounds__(256) void cvt_all(
    const float* __restrict__ q, const float* __restrict__ k, const float* __restrict__ v,
    const float* __restrict__ wq, const float* __restrict__ wk,
    const float* __restrict__ wv, const float* __restrict__ wo,
    u16* __restrict__ Xb, u16* __restrict__ Wb)
{
  const int TOT = 3670016;                     // chunks of 8 floats
  for (int c = blockIdx.x * 256 + threadIdx.x; c < TOT; c += gridDim.x * 256) {
    const float* s; u16* d;
    if (c < 3145728) {
      int z = c >> 20, off = c & 1048575;
      s = ((z == 0) ? q : (z == 1) ? k : v) + (size_t)off * 8;
      d = Xb + (size_t)c * 8;
    } else {
      int wc = c - 3145728;
      int z = wc >> 17, off = wc & 131071;
      s = ((z == 0) ? wq : (z == 1) ? wk : (z == 2) ? wv : wo) + (size_t)off * 8;
      d = Wb + (size_t)wc * 8;
    }
    float4 a = ((const float4*)s)[0], b = ((const float4*)s)[1];
    *(short8*)d = cvt8(a, b);
  }
}

// -------- bf16 GEMM core: C(128x128) = A(128xK) * B(128xK)^T, K=1024 --------
// m97 structure: global_load_lds width-16 staging into linear LDS [128][64].
// SWAP=1 computes with operands reversed (acc holds C^T mapping).
template<int SWAP>
__device__ __forceinline__ void gemm_core_bf16(const u16* __restrict__ A,
                                               const u16* __restrict__ B,
                                               u16* As, u16* Bs,
                                               f32x4 acc[4][4])
{
  const int tid = threadIdx.x;
  const int lane = tid & 63, wid = tid >> 6;
  const int lo = lane & 15, hi = lane >> 4;
  const int wr0 = (wid >> 1) * 64, wc0 = (wid & 1) * 64;

  for (int k0 = 0; k0 < 1024; k0 += 64) {
    __syncthreads();
#pragma unroll
    for (int it = 0; it < 4; ++it) {
      int idx = it * 256 + tid;            // 1024 chunks of 16B per matrix
      int row = idx >> 3, slot = idx & 7;
      cp16(A + (size_t)row * 1024 + k0 + slot * 8, As + (size_t)idx * 8);
      cp16(B + (size_t)row * 1024 + k0 + slot * 8, Bs + (size_t)idx * 8);
    }
    __syncthreads();
#pragma unroll
    for (int kk = 0; kk < 2; ++kk) {
      short8 af[4], bfr[4];
      int slot = kk * 4 + hi;
#pragma unroll
      for (int i = 0; i < 4; ++i)
        af[i] = *(const short8*)(&As[(wr0 + i * 16 + lo) * 64 + slot * 8]);
#pragma unroll
      for (int j = 0; j < 4; ++j)
        bfr[j] = *(const short8*)(&Bs[(wc0 + j * 16 + lo) * 64 + slot * 8]);
#pragma unroll
      for (int i = 0; i < 4; ++i)
#pragma unroll
        for (int j = 0; j < 4; ++j)
          acc[i][j] = SWAP
            ? __builtin_amdgcn_mfma_f32_16x16x32_bf16(bfr[j], af[i], acc[i][j], 0, 0, 0)
            : __builtin_amdgcn_mfma_f32_16x16x32_bf16(af[i], bfr[j], acc[i][j], 0, 0, 0);
    }
  }
}

// z=0: Q*0.125 -> Qh[bh][s][d]; z=1: K -> Kh[bh][s][d]; z=2: V -> Vt[bh][d][s]
__global__ __launch_bounds__(256) void gemm_qkv(
    const u16* __restrict__ Xb, const u16* __restrict__ Wb,
    const float* __restrict__ bq, const float* __restrict__ bk, const float* __restrict__ bv,
    u16* __restrict__ Qh, u16* __restrict__ Kh, u16* __restrict__ Vt)
{
  __shared__ __align__(16) u16 As[128 * 64];
  __shared__ __align__(16) u16 Bs[128 * 64];
  const int z = blockIdx.z;
  const int bm0 = blockIdx.x * 128, bn0 = blockIdx.y * 128;
  const u16* A = Xb + (size_t)z * 8388608 + (size_t)bm0 * 1024;
  const u16* W = Wb + (size_t)z * 1048576 + (size_t)bn0 * 1024;
  const float* bias = (z == 0) ? bq : (z == 1) ? bk : bv;

  f32x4 acc[4][4] = {};
  if (z < 2) gemm_core_bf16<0>(A, W, As, Bs, acc);
  else       gemm_core_bf16<1>(A, W, As, Bs, acc);

  const int lane = threadIdx.x & 63, wid = threadIdx.x >> 6;
  const int lo = lane & 15, hi = lane >> 4;
  const int wr0 = (wid >> 1) * 64, wc0 = (wid & 1) * 64;

  if (z < 2) {
    u16* out = (z == 0) ? Qh : Kh;
    const float sc = (z == 0) ? 0.125f : 1.0f;
#pragma unroll
    for (int j = 0; j < 4; ++j) {
      int n = bn0 + wc0 + j * 16 + lo;
      float bb = bias[n];
      int h = n >> 6, d = n & 63;
#pragma unroll
      for (int i = 0; i < 4; ++i)
#pragma unroll
        for (int r = 0; r < 4; ++r) {
          int m = bm0 + wr0 + i * 16 + hi * 4 + r;
          int b = m >> 11, s = m & 2047;
          float v = (acc[i][j][r] + bb) * sc;
          out[(((size_t)(b * 16 + h)) * 2048 + s) * 64 + d] = f2bf(v);
        }
    }
  } else {
    // swapped: lane&15 = A-row (s), hi*4+r = W-row (channel n)
#pragma unroll
    for (int j = 0; j < 4; ++j) {
#pragma unroll
      for (int r = 0; r < 4; ++r) {
        int n = bn0 + wc0 + j * 16 + hi * 4 + r;
        float bb = bias[n];
        int h = n >> 6, d = n & 63;
#pragma unroll
        for (int i = 0; i < 4; ++i) {
          int m = bm0 + wr0 + i * 16 + lo;
          int b = m >> 11, s = m & 2047;
          Vt[(((size_t)(b * 16 + h)) * 64 + d) * 2048 + s] = f2bf(acc[i][j][r] + bb);
        }
      }
    }
  }
}

__global__ __launch_bounds__(256) void gemm_out(
    const u16* __restrict__ ATT, const u16* __restrict__ Wo,
    const float* __restrict__ bo, float* __restrict__ out)
{
  __shared__ __align__(16) u16 As[128 * 64];
  __shared__ __align__(16) u16 Bs[128 * 64];
  const int bm0 = blockIdx.x * 128, bn0 = blockIdx.y * 128;
  f32x4 acc[4][4] = {};
  gemm_core_bf16<0>(ATT + (size_t)bm0 * 1024, Wo + (size_t)bn0 * 1024, As, Bs, acc);

  const int lane = threadIdx.x & 63, wid = threadIdx.x >> 6;
  const int lo = lane & 15, hi = lane >> 4;
  const int wr0 = (wid >> 1) * 64, wc0 = (wid & 1) * 64;
#pragma unroll
  for (int j = 0; j < 4; ++j) {
    int n = bn0 + wc0 + j * 16 + lo;
    float bb = bo[n];
#pragma unroll
    for (int i = 0; i < 4; ++i)
#pragma unroll
      for (int r = 0; r < 4; ++r) {
        int m = bm0 + wr0 + i * 16 + hi * 4 + r;
        out[(size_t)m * 1024 + n] = acc[i][j][r] + bb;
      }
  }
}

// -------- fused attention: swapped QK^T, two-pass softmax, attn+PV ----------
// Block = 64 q-rows of one (b,h); 4 waves x 16 q. KVBLK=64. Q pre-scaled.
// sc[j] = mfma(K,Q): lane&15 = q (lo), hi*4+r = t within 16-tile j.
__global__ __launch_bounds__(256) void attn_fused(
    const u16* __restrict__ Qh, const u16* __restrict__ Kh,
    const u16* __restrict__ Vt, float* __restrict__ attnOut,
    u16* __restrict__ ATT)
{
  __shared__ __align__(16) u16 Qs[64 * 64];
  __shared__ __align__(16) u16 Ks[64 * 64];
  __shared__ __align__(16) u16 Vs[64 * 64];
  __shared__ __align__(16) u16 Ps[64 * 64];
  const int tid = threadIdx.x, lane = tid & 63, wid = tid >> 6;
  const int lo = lane & 15, hi = lane >> 4;
  // XCD swizzle: grid 2048 flat; XCD i owns bh in [i*8, i*8+8)
  const int bid = blockIdx.x;
  const int xcd = bid & 7, idx = bid >> 3;
  const int bh = xcd * 8 + (idx >> 5);
  const int q0 = (idx & 31) * 64;
  const int wq0 = wid * 16;

  const u16* Qg  = Qh + ((size_t)bh * 2048 + q0) * 64;
  const u16* Kg0 = Kh + (size_t)bh * 2048 * 64;
  const u16* Vg0 = Vt + (size_t)bh * 64 * 2048;

#pragma unroll
  for (int it = 0; it < 2; ++it) {
    int i2 = it * 256 + tid;
    int row = i2 >> 3, slot = i2 & 7;
    short8 v = *(const short8*)(Qg + row * 64 + slot * 8);
    *(short8*)(&Qs[row * 64 + ((slot ^ (row & 7)) << 3)]) = v;
  }
  __syncthreads();
  short8 qa[2];
#pragma unroll
  for (int kk = 0; kk < 2; ++kk) {
    int row = wq0 + lo, slot = kk * 4 + hi;
    qa[kk] = *(const short8*)(&Qs[row * 64 + ((slot ^ (row & 7)) << 3)]);
  }

  float m_q = -1e30f, l_q = 0.f;

  // ---- pass 1: softmax stats (per-lane q = wq0+lo) ----
  for (int kt = 0; kt < 32; ++kt) {
    __syncthreads();
    int t0 = kt * 64;
#pragma unroll
    for (int it = 0; it < 2; ++it) {
      int i2 = it * 256 + tid;
      int row = i2 >> 3, slot = i2 & 7;
      short8 v = *(const short8*)(Kg0 + (size_t)(t0 + row) * 64 + slot * 8);
      *(short8*)(&Ks[row * 64 + ((slot ^ (row & 7)) << 3)]) = v;
    }
    __syncthreads();
    f32x4 sc[4] = {};
#pragma unroll
    for (int kk = 0; kk < 2; ++kk) {
      int slot = kk * 4 + hi;
#pragma unroll
      for (int j = 0; j < 4; ++j) {
        int row = j * 16 + lo;
        short8 kb = *(const short8*)(&Ks[row * 64 + ((slot ^ (row & 7)) << 3)]);
        sc[j] = __builtin_amdgcn_mfma_f32_16x16x32_bf16(kb, qa[kk], sc[j], 0, 0, 0);
      }
    }
    float tm = sc[0][0];
#pragma unroll
    for (int j = 0; j < 4; ++j)
#pragma unroll
      for (int r = 0; r < 4; ++r) tm = fmaxf(tm, sc[j][r]);
    tm = fmaxf(tm, __shfl_xor(tm, 16));
    tm = fmaxf(tm, __shfl_xor(tm, 32));
    float nm = fmaxf(m_q, tm);
    float ts = 0.f;
#pragma unroll
    for (int j = 0; j < 4; ++j)
#pragma unroll
      for (int r = 0; r < 4; ++r) ts += __expf(sc[j][r] - nm);
    ts += __shfl_xor(ts, 16);
    ts += __shfl_xor(ts, 32);
    l_q = l_q * __expf(m_q - nm) + ts;
    m_q = nm;
  }
  const float inv_l = 1.0f / l_q;

  // ---- pass 2: recompute S, normalize, write attn (f32x4 NT), PV ----
  f32x4 oacc[4] = {};
  for (int kt = 0; kt < 32; ++kt) {
    __syncthreads();
    int t0 = kt * 64;
#pragma unroll
    for (int it = 0; it < 2; ++it) {
      int i2 = it * 256 + tid;
      int row = i2 >> 3, slot = i2 & 7;
      short8 v = *(const short8*)(Kg0 + (size_t)(t0 + row) * 64 + slot * 8);
      *(short8*)(&Ks[row * 64 + ((slot ^ (row & 7)) << 3)]) = v;
      short8 w = *(const short8*)(Vg0 + (size_t)row * 2048 + t0 + slot * 8);
      *(short8*)(&Vs[row * 64 + ((slot ^ (row & 7)) << 3)]) = w;
    }
    __syncthreads();
    f32x4 sc[4] = {};
#pragma unroll
    for (int kk = 0; kk < 2; ++kk) {
      int slot = kk * 4 + hi;
#pragma unroll
      for (int j = 0; j < 4; ++j) {
        int row = j * 16 + lo;
        short8 kb = *(const short8*)(&Ks[row * 64 + ((slot ^ (row & 7)) << 3)]);
        sc[j] = __builtin_amdgcn_mfma_f32_16x16x32_bf16(kb, qa[kk], sc[j], 0, 0, 0);
      }
    }
    float p[4][4];
#pragma unroll
    for (int j = 0; j < 4; ++j)
#pragma unroll
      for (int r = 0; r < 4; ++r) p[j][r] = __expf(sc[j][r] - m_q) * inv_l;

    float* aOut = attnOut + ((size_t)bh * 2048 + q0 + wq0 + lo) * 2048 + t0 + hi * 4;
#pragma unroll
    for (int j = 0; j < 4; ++j) {
      f32x4 f4;
      f4[0] = p[j][0]; f4[1] = p[j][1]; f4[2] = p[j][2]; f4[3] = p[j][3];
      __builtin_nontemporal_store(f4, (f32x4*)(aOut + j * 16));
    }
    // P -> LDS (wave-private rows; 8B packed, swizzled) then PV
    const int qr = wq0 + lo;
#pragma unroll
    for (int j = 0; j < 4; ++j) {
      unsigned u0 = (unsigned)f2bf(p[j][0]) | ((unsigned)f2bf(p[j][1]) << 16);
      unsigned u1 = (unsigned)f2bf(p[j][2]) | ((unsigned)f2bf(p[j][3]) << 16);
      int byte = (qr * 128 + j * 32 + hi * 8) ^ ((qr & 7) << 4);
      uint2 uu; uu.x = u0; uu.y = u1;
      *(uint2*)((char*)Ps + byte) = uu;
    }
#pragma unroll
    for (int c = 0; c < 2; ++c) {
      int byte = (qr * 128 + c * 64 + hi * 16) ^ ((qr & 7) << 4);
      short8 pa = *(const short8*)((char*)Ps + byte);
      int slot = c * 4 + hi;
#pragma unroll
      for (int j = 0; j < 4; ++j) {
        int vrow = j * 16 + lo;
        short8 vb = *(const short8*)(&Vs[vrow * 64 + ((slot ^ (vrow & 7)) << 3)]);
        oacc[j] = __builtin_amdgcn_mfma_f32_16x16x32_bf16(pa, vb, oacc[j], 0, 0, 0);
      }
    }
  }
  // attended -> ATT[b*2048+q][h*64+d] bf16 (oacc: lane&15=d, hi*4+r=q)
  const int b = bh >> 4, h = bh & 15;
#pragma unroll
  for (int j = 0; j < 4; ++j)
#pragma unroll
    for (int r = 0; r < 4; ++r) {
      int ql = wq0 + hi * 4 + r;
      int d = j * 16 + lo;
      size_t row = (size_t)b * 2048 + q0 + ql;
      ATT[row * 1024 + h * 64 + d] = f2bf(oacc[j][r]);
    }
}

extern "C" void kernel_launch(void* const* d_in, const int* in_sizes, int n_in,
                              void* d_out, int out_size, void* d_ws, size_t ws_size,
                              hipStream_t stream) {
  const float* query = (const float*)d_in[0];
  const float* key   = (const float*)d_in[1];
  const float* value = (const float*)d_in[2];
  const float* Wq = (const float*)d_in[3];
  const float* bq = (const float*)d_in[4];
  const float* Wk = (const float*)d_in[5];
  const float* bk = (const float*)d_in[6];
  const float* Wv = (const float*)d_in[7];
  const float* bv = (const float*)d_in[8];
  const float* Wo = (const float*)d_in[9];
  const float* bo = (const float*)d_in[10];

  // ws layout (u16 units):
  u16* Xb  = (u16*)d_ws;               // 25165824 (q|k|v bf16)
  u16* Wb  = Xb + 25165824;            // 4194304  (Wq|Wk|Wv|Wo bf16)
  u16* Qh  = Wb + 4194304;             // 8388608
  u16* Kh  = Qh + 8388608;             // 8388608
  u16* Vt  = Kh + 8388608;             // 8388608   (total ~109 MB)
  u16* ATT = Xb;                        // alias Xb (dead after gemm_qkv)

  float* outO  = (float*)d_out;
  float* attnO = outO + (size_t)8388608;

  cvt_all<<<2048, 256, 0, stream>>>(query, key, value, Wq, Wk, Wv, Wo, Xb, Wb);
  gemm_qkv<<<dim3(64, 8, 3), 256, 0, stream>>>(Xb, Wb, bq, bk, bv, Qh, Kh, Vt);
  attn_fused<<<2048, 256, 0, stream>>>(Qh, Kh, Vt, attnO, ATT);
  gemm_out<<<dim3(64, 8), 256, 0, stream>>>(ATT, Wb + 3145728, bo, outO);
}